// Round 3
// baseline (300.845 us; speedup 1.0000x reference)
//
#include <hip/hip_runtime.h>

// Problem constants
#define DD 96
#define HH 96
#define WW 96
#define BN 76                 // BATCH(4) * N_LANDMARKS(19)
#define SLICE4 (HH*WW/4)      // 2304 float4 per (bn,d) slice
#define W4R (WW/4)            // 24 float4 per w-row
#define NSLICE (BN*DD)        // 7296 blocks

// ---------------------------------------------------------------------------
// Single fused kernel. One block per (bn,d) slice:
//   phase A: recompute the 3x96 separable exp tables in-block (cheap, hidden)
//   phase B: wave-0 shuffle reduce -> normalization 1/s
//   phase C: stream the 36 KB slice, |pred - ew*fh| sum
//   phase D: last-block-done reduction of 7296 partials -> final scalar
// Deterministic: every part[bx] is a fixed function of inputs, and the
// last block reduces them in a fixed order.
// ---------------------------------------------------------------------------
__global__ void __launch_bounds__(256) fused_kernel(
        const float*  __restrict__ labels,
        const float4* __restrict__ pred,
        float* __restrict__ part,          // [NSLICE]
        unsigned int* __restrict__ counter,
        float* __restrict__ out) {
    const int bx  = blockIdx.x;
    const int bn  = bx / DD;
    const int d   = bx - bn * DD;
    const int tid = threadIdx.x;

    __shared__ __align__(16) float ew_s[96];
    __shared__ float eh_s[96];
    __shared__ float ed_s[96];
    __shared__ float fh_s[96];
    __shared__ float sums_s[3];
    __shared__ float wsA[4], wsC[4];
    __shared__ int   last_s;

    // labels are block-uniform -> scalar loads
    const float lx = labels[bn * 3 + 0];
    const float ly = labels[bn * 3 + 1];
    const float lz = labels[bn * 3 + 2];
    const float x = lx * 95.0f;   // scale = [W-1, H-1, D-1] = 95
    const float y = ly * 95.0f;
    const float z = lz * 95.0f;

    // phase A: tables
    if (tid < 96) {
        const float fi = (float)tid;
        const float dx = fi - x, dy = fi - y, dz = fi - z;
        ew_s[tid] = __expf(-dx * dx * 0.125f);   // 1/(2*sigma^2) = 1/8
        eh_s[tid] = __expf(-dy * dy * 0.125f);
        ed_s[tid] = __expf(-dz * dz * 0.125f);
    }
    __syncthreads();

    // phase B: sums via wave-0 shuffle reduce (96 = 64 + 32)
    if (tid < 64) {
        float a = ew_s[tid], b = eh_s[tid], c = ed_s[tid];
        if (tid < 32) { a += ew_s[tid + 64]; b += eh_s[tid + 64]; c += ed_s[tid + 64]; }
        for (int off = 32; off > 0; off >>= 1) {
            a += __shfl_down(a, off, 64);
            b += __shfl_down(b, off, 64);
            c += __shfl_down(c, off, 64);
        }
        if (tid == 0) { sums_s[0] = a; sums_s[1] = b; sums_s[2] = c; }
    }
    __syncthreads();

    const float s   = sums_s[0] * sums_s[1] * sums_s[2];
    const float inv = (s > 0.0f) ? (1.0f / s) : 1.0f;   // jnp.where(s>0, hm/s, hm)
    if (tid < 96) fh_s[tid] = eh_s[tid] * (ed_s[d] * inv);
    __syncthreads();

    // phase C: stream the slice (contiguous, coalesced float4)
    const float4* p0  = pred + (size_t)bx * SLICE4;
    const float4* ew4 = reinterpret_cast<const float4*>(ew_s);
    float acc = 0.0f;
    #pragma unroll
    for (int k = 0; k < 9; ++k) {
        const int t  = tid + k * 256;
        const int h  = t / W4R;
        const int w4 = t - h * W4R;
        const float4 p = p0[t];
        const float4 e = ew4[w4];
        const float  f = fh_s[h];
        acc += fabsf(p.x - e.x * f) + fabsf(p.y - e.y * f)
             + fabsf(p.z - e.z * f) + fabsf(p.w - e.w * f);
    }
    acc *= (lx >= 0.0f) ? 1.0f : 0.0f;   // validity mask (block-uniform)

    // block reduce -> one partial per block
    for (int off = 32; off > 0; off >>= 1)
        acc += __shfl_down(acc, off, 64);
    const int lane = tid & 63;
    const int wid  = tid >> 6;
    if (lane == 0) wsA[wid] = acc;
    __syncthreads();
    if (tid == 0) {
        part[bx] = wsA[0] + wsA[1] + wsA[2] + wsA[3];
        __threadfence();                            // release: part[] visible device-wide
        const unsigned int prev = atomicAdd(counter, 1u);
        last_s = (prev == NSLICE - 1) ? 1 : 0;
    }
    __syncthreads();

    // phase D: last arriving block reduces all partials (fixed order)
    if (last_s) {
        __threadfence();                            // acquire side
        float tot = 0.0f;
        for (int i = tid; i < NSLICE; i += 256) tot += part[i];
        float cnt = 0.0f;
        if (tid < BN) cnt = (labels[tid * 3] >= 0.0f) ? 1.0f : 0.0f;

        for (int off = 32; off > 0; off >>= 1) {
            tot += __shfl_down(tot, off, 64);
            cnt += __shfl_down(cnt, off, 64);
        }
        if (lane == 0) { wsA[wid] = tot; wsC[wid] = cnt; }
        __syncthreads();
        if (tid == 0) {
            const float t2 = wsA[0] + wsA[1] + wsA[2] + wsA[3];
            const float c2 = wsC[0] + wsC[1] + wsC[2] + wsC[3];
            out[0] = t2 / (c2 + 1e-8f);
        }
    }
}

extern "C" void kernel_launch(void* const* d_in, const int* in_sizes, int n_in,
                              void* d_out, int out_size, void* d_ws, size_t ws_size,
                              hipStream_t stream) {
    const float* pred   = (const float*)d_in[0];   // (4,19,96,96,96) f32
    const float* labels = (const float*)d_in[1];   // (4,19,3) f32
    float* out = (float*)d_out;

    char* ws = (char*)d_ws;
    unsigned int* counter = (unsigned int*)(ws + 0);
    float*        part    = (float*)(ws + 256);     // 7296 floats

    // counter must be 0 at the start of every call (ws is not re-poisoned)
    hipMemsetAsync(counter, 0, 4, stream);

    fused_kernel<<<NSLICE, 256, 0, stream>>>(labels, (const float4*)pred,
                                             part, counter, out);
}

// Round 4
// 51.628 us; speedup vs baseline: 5.8272x; 5.8272x over previous
//
#include <hip/hip_runtime.h>

// Problem constants
#define DD 96
#define HH 96
#define WW 96
#define BN 76                 // BATCH(4) * N_LANDMARKS(19)
#define SLICE4 (HH*WW/4)      // 2304 float4 per (bn,d) slice
#define W4R (WW/4)            // 24 float4 per w-row
#define NSLICE (BN*DD)        // 7296 blocks
#define NT 384                // 6 waves; 2304/384 = 6 iters; tid%24 = const w4

// ---------------------------------------------------------------------------
// Kernel 1: one block per (bn,d) slice. Fused tables + streaming loss.
//   phase A: recompute 3x96 separable exp tables in-block (cheap)
//   phase B: wave-0 shuffle reduce -> normalization 1/s
//   phase C: stream the 36 KB slice; each thread owns one w4 column (ew in
//            registers), 6 independent float4 loads in flight
// One partial store per block. No atomics, no fences -> no serialization.
// ---------------------------------------------------------------------------
__global__ void __launch_bounds__(NT) loss_kernel(
        const float*  __restrict__ labels,
        const float4* __restrict__ pred,
        float* __restrict__ part) {        // [NSLICE]
    const int bx  = blockIdx.x;
    const int bn  = bx / DD;
    const int d   = bx - bn * DD;
    const int tid = threadIdx.x;

    __shared__ __align__(16) float ew_s[96];
    __shared__ float eh_s[96];
    __shared__ float ed_s[96];
    __shared__ float fh_s[96];
    __shared__ float sums_s[3];
    __shared__ float wsum[NT / 64];

    // labels are block-uniform -> scalar loads
    const float lx = labels[bn * 3 + 0];
    const float ly = labels[bn * 3 + 1];
    const float lz = labels[bn * 3 + 2];
    const float x = lx * 95.0f;   // scale = [W-1, H-1, D-1] = 95
    const float y = ly * 95.0f;
    const float z = lz * 95.0f;

    // phase A: tables
    if (tid < 96) {
        const float fi = (float)tid;
        const float dx = fi - x, dy = fi - y, dz = fi - z;
        ew_s[tid] = __expf(-dx * dx * 0.125f);   // 1/(2*sigma^2) = 1/8
        eh_s[tid] = __expf(-dy * dy * 0.125f);
        ed_s[tid] = __expf(-dz * dz * 0.125f);
    }
    __syncthreads();

    // phase B: sums via wave-0 shuffle reduce (96 = 64 + 32)
    if (tid < 64) {
        float a = ew_s[tid], b = eh_s[tid], c = ed_s[tid];
        if (tid < 32) { a += ew_s[tid + 64]; b += eh_s[tid + 64]; c += ed_s[tid + 64]; }
        for (int off = 32; off > 0; off >>= 1) {
            a += __shfl_down(a, off, 64);
            b += __shfl_down(b, off, 64);
            c += __shfl_down(c, off, 64);
        }
        if (tid == 0) { sums_s[0] = a; sums_s[1] = b; sums_s[2] = c; }
    }
    __syncthreads();

    const float s   = sums_s[0] * sums_s[1] * sums_s[2];
    const float inv = (s > 0.0f) ? (1.0f / s) : 1.0f;   // jnp.where(s>0, hm/s, hm)
    if (tid < 96) fh_s[tid] = eh_s[tid] * (ed_s[d] * inv);
    __syncthreads();

    // phase C: stream. thread -> (h0 = tid/24, w4 = tid%24); h = h0 + 16k.
    const int w4 = tid % W4R;
    const float4 e = reinterpret_cast<const float4*>(ew_s)[w4];   // registers

    const float4* p0 = pred + (size_t)bx * SLICE4;
    float acc = 0.0f;
    #pragma unroll
    for (int k = 0; k < 6; ++k) {
        const int t = tid + k * NT;          // = (h0 + 16k)*24 + w4
        const float4 p = p0[t];
        const float  f = fh_s[t / W4R];      // broadcast within 24-lane groups
        acc += fabsf(p.x - e.x * f) + fabsf(p.y - e.y * f)
             + fabsf(p.z - e.z * f) + fabsf(p.w - e.w * f);
    }
    acc *= (lx >= 0.0f) ? 1.0f : 0.0f;       // validity mask (block-uniform)

    // block reduce -> one partial per block
    for (int off = 32; off > 0; off >>= 1)
        acc += __shfl_down(acc, off, 64);
    const int lane = tid & 63;
    const int wid  = tid >> 6;
    if (lane == 0) wsum[wid] = acc;
    __syncthreads();
    if (tid == 0) {
        float t2 = 0.0f;
        #pragma unroll
        for (int i = 0; i < NT / 64; ++i) t2 += wsum[i];
        part[bx] = t2;
    }
}

// ---------------------------------------------------------------------------
// Kernel 2: reduce 7296 partials + validity count, write final scalar.
// ---------------------------------------------------------------------------
__global__ void __launch_bounds__(256) finalize_kernel(
        const float* __restrict__ part,
        const float* __restrict__ labels,
        float* __restrict__ out) {
    const int tid = threadIdx.x;

    float acc = 0.0f;
    for (int i = tid; i < NSLICE; i += 256) acc += part[i];
    float cnt = (tid < BN) ? ((labels[tid * 3] >= 0.0f) ? 1.0f : 0.0f) : 0.0f;

    for (int off = 32; off > 0; off >>= 1) {
        acc += __shfl_down(acc, off, 64);
        cnt += __shfl_down(cnt, off, 64);
    }
    __shared__ float wsA[4], wsC[4];
    const int lane = tid & 63;
    const int wid  = tid >> 6;
    if (lane == 0) { wsA[wid] = acc; wsC[wid] = cnt; }
    __syncthreads();
    if (tid == 0) {
        const float tot = wsA[0] + wsA[1] + wsA[2] + wsA[3];
        const float c   = wsC[0] + wsC[1] + wsC[2] + wsC[3];
        out[0] = tot / (c + 1e-8f);
    }
}

extern "C" void kernel_launch(void* const* d_in, const int* in_sizes, int n_in,
                              void* d_out, int out_size, void* d_ws, size_t ws_size,
                              hipStream_t stream) {
    const float* pred   = (const float*)d_in[0];   // (4,19,96,96,96) f32
    const float* labels = (const float*)d_in[1];   // (4,19,3) f32
    float* out = (float*)d_out;

    float* part = (float*)d_ws;                    // 7296 floats

    loss_kernel<<<NSLICE, NT, 0, stream>>>(labels, (const float4*)pred, part);
    finalize_kernel<<<1, 256, 0, stream>>>(part, labels, out);
}

// Round 5
// 46.365 us; speedup vs baseline: 6.4886x; 1.1135x over previous
//
#include <hip/hip_runtime.h>

// Problem constants
#define DD 96
#define HH 96
#define WW 96
#define BN 76                 // BATCH(4) * N_LANDMARKS(19)
#define SLICE4 (HH*WW/4)      // 2304 float4 per (bn,d) slice
#define W4R (WW/4)            // 24 float4 per w-row
#define DG 6                  // d-slices per block
#define NGRP (DD/DG)          // 16 groups per bn
#define NBLK (BN*NGRP)        // 1216 blocks -> all co-resident (5/CU x 6 waves)
#define NT 384                // 6 waves; 2304/384 = 6 float4 iters per slice

// ---------------------------------------------------------------------------
// Kernel 1: one block per (bn, d-group). Fused tables + streaming loss.
//   phase A: recompute 3x96 separable exp tables in-block (paid once per 6
//            slices = 216 KB streamed, ~2.5% overhead)
//   phase B: wave-0 shuffle reduce -> normalization 1/s (folded into eh)
//   phase C: per-thread static (h0,w4): ew -> 1 register float4,
//            eh*inv -> 6 registers. Stream loop = 1 global float4 +
//            ~10 VALU; one LDS broadcast (ed) per slice. No divides.
// One partial store per block. No atomics, no fences.
// ---------------------------------------------------------------------------
__global__ void __launch_bounds__(NT) loss_kernel(
        const float*  __restrict__ labels,
        const float4* __restrict__ pred,
        float* __restrict__ part) {        // [NBLK]
    const int bx  = blockIdx.x;
    const int bn  = bx / NGRP;
    const int d0  = (bx - bn * NGRP) * DG;
    const int tid = threadIdx.x;

    __shared__ __align__(16) float ew_s[96];
    __shared__ float eh_s[96];
    __shared__ float ed_s[96];
    __shared__ float fh_s[96];             // eh * inv
    __shared__ float sums_s[3];
    __shared__ float wsum[NT / 64];

    // labels are block-uniform -> scalar loads
    const float lx = labels[bn * 3 + 0];
    const float ly = labels[bn * 3 + 1];
    const float lz = labels[bn * 3 + 2];
    const float x = lx * 95.0f;   // scale = [W-1, H-1, D-1] = 95
    const float y = ly * 95.0f;
    const float z = lz * 95.0f;

    // phase A: tables
    if (tid < 96) {
        const float fi = (float)tid;
        const float dx = fi - x, dy = fi - y, dz = fi - z;
        ew_s[tid] = __expf(-dx * dx * 0.125f);   // 1/(2*sigma^2) = 1/8
        eh_s[tid] = __expf(-dy * dy * 0.125f);
        ed_s[tid] = __expf(-dz * dz * 0.125f);
    }
    __syncthreads();

    // phase B: sums via wave-0 shuffle reduce (96 = 64 + 32)
    if (tid < 64) {
        float a = ew_s[tid], b = eh_s[tid], c = ed_s[tid];
        if (tid < 32) { a += ew_s[tid + 64]; b += eh_s[tid + 64]; c += ed_s[tid + 64]; }
        for (int off = 32; off > 0; off >>= 1) {
            a += __shfl_down(a, off, 64);
            b += __shfl_down(b, off, 64);
            c += __shfl_down(c, off, 64);
        }
        if (tid == 0) { sums_s[0] = a; sums_s[1] = b; sums_s[2] = c; }
    }
    __syncthreads();

    const float s   = sums_s[0] * sums_s[1] * sums_s[2];
    const float inv = (s > 0.0f) ? (1.0f / s) : 1.0f;   // jnp.where(s>0, hm/s, hm)
    if (tid < 96) fh_s[tid] = eh_s[tid] * inv;
    __syncthreads();

    // per-thread static indices: h = h0 + 16k, w4 fixed
    const int h0 = tid / W4R;
    const int w4 = tid - h0 * W4R;
    const float4 e = reinterpret_cast<const float4*>(ew_s)[w4];
    float fhr[6];
    #pragma unroll
    for (int k = 0; k < 6; ++k) fhr[k] = fh_s[h0 + 16 * k];

    // phase C: stream DG slices (contiguous 216 KB, coalesced float4)
    const float4* p0 = pred + (size_t)(bn * DD + d0) * SLICE4 + tid;
    float acc = 0.0f;
    #pragma unroll 2
    for (int dd = 0; dd < DG; ++dd) {
        const float edv = ed_s[d0 + dd];         // LDS broadcast, once/slice
        #pragma unroll
        for (int k = 0; k < 6; ++k) {
            const float4 p = p0[dd * SLICE4 + k * NT];
            const float  f = fhr[k] * edv;
            acc += fabsf(p.x - e.x * f) + fabsf(p.y - e.y * f)
                 + fabsf(p.z - e.z * f) + fabsf(p.w - e.w * f);
        }
    }
    acc *= (lx >= 0.0f) ? 1.0f : 0.0f;           // validity mask (block-uniform)

    // block reduce -> one partial per block
    for (int off = 32; off > 0; off >>= 1)
        acc += __shfl_down(acc, off, 64);
    const int lane = tid & 63;
    const int wid  = tid >> 6;
    if (lane == 0) wsum[wid] = acc;
    __syncthreads();
    if (tid == 0) {
        float t2 = 0.0f;
        #pragma unroll
        for (int i = 0; i < NT / 64; ++i) t2 += wsum[i];
        part[bx] = t2;
    }
}

// ---------------------------------------------------------------------------
// Kernel 2: reduce 1216 partials + validity count, write final scalar.
// ---------------------------------------------------------------------------
__global__ void __launch_bounds__(256) finalize_kernel(
        const float* __restrict__ part,
        const float* __restrict__ labels,
        float* __restrict__ out) {
    const int tid = threadIdx.x;

    float acc = 0.0f;
    for (int i = tid; i < NBLK; i += 256) acc += part[i];
    float cnt = (tid < BN) ? ((labels[tid * 3] >= 0.0f) ? 1.0f : 0.0f) : 0.0f;

    for (int off = 32; off > 0; off >>= 1) {
        acc += __shfl_down(acc, off, 64);
        cnt += __shfl_down(cnt, off, 64);
    }
    __shared__ float wsA[4], wsC[4];
    const int lane = tid & 63;
    const int wid  = tid >> 6;
    if (lane == 0) { wsA[wid] = acc; wsC[wid] = cnt; }
    __syncthreads();
    if (tid == 0) {
        const float tot = wsA[0] + wsA[1] + wsA[2] + wsA[3];
        const float c   = wsC[0] + wsC[1] + wsC[2] + wsC[3];
        out[0] = tot / (c + 1e-8f);
    }
}

extern "C" void kernel_launch(void* const* d_in, const int* in_sizes, int n_in,
                              void* d_out, int out_size, void* d_ws, size_t ws_size,
                              hipStream_t stream) {
    const float* pred   = (const float*)d_in[0];   // (4,19,96,96,96) f32
    const float* labels = (const float*)d_in[1];   // (4,19,3) f32
    float* out = (float*)d_out;

    float* part = (float*)d_ws;                    // 1216 floats

    loss_kernel<<<NBLK, NT, 0, stream>>>(labels, (const float4*)pred, part);
    finalize_kernel<<<1, 256, 0, stream>>>(part, labels, out);
}

// Round 6
// 45.997 us; speedup vs baseline: 6.5405x; 1.0080x over previous
//
#include <hip/hip_runtime.h>

// Problem constants
#define DD 96
#define HH 96
#define WW 96
#define BN 76                 // BATCH(4) * N_LANDMARKS(19)
#define SLICE4 (HH*WW/4)      // 2304 float4 per (bn,d) slice
#define W4R (WW/4)            // 24 float4 per w-row
#define DG 2                  // d-slices per block (small quantum -> small tail)
#define NGRP (DD/DG)          // 48 groups per bn
#define NBLK (BN*NGRP)        // 3648 blocks, ~2.9us quantum, dynamic balance
#define NT 384                // 6 waves; 2304/384 = 6 float4 iters per slice

// ---------------------------------------------------------------------------
// Kernel 1: one block per (bn, d-group). Fused tables + streaming loss.
//   phase A: recompute 3x96 separable exp tables in-block (hidden under the
//            other ~4 co-resident blocks' streams)
//   phase B: wave-0 shuffle reduce -> normalization 1/s (folded into eh)
//   phase C: per-thread static (h0,w4): ew -> 1 register float4,
//            eh*inv -> 6 registers. 12 independent float4 loads in flight.
// One partial store per block. No atomics, no fences.
// ---------------------------------------------------------------------------
__global__ void __launch_bounds__(NT) loss_kernel(
        const float*  __restrict__ labels,
        const float4* __restrict__ pred,
        float* __restrict__ part) {        // [NBLK]
    const int bx  = blockIdx.x;
    const int bn  = bx / NGRP;
    const int d0  = (bx - bn * NGRP) * DG;
    const int tid = threadIdx.x;

    __shared__ __align__(16) float ew_s[96];
    __shared__ float eh_s[96];
    __shared__ float ed_s[96];
    __shared__ float fh_s[96];             // eh * inv
    __shared__ float sums_s[3];
    __shared__ float wsum[NT / 64];

    // labels are block-uniform -> scalar loads
    const float lx = labels[bn * 3 + 0];
    const float ly = labels[bn * 3 + 1];
    const float lz = labels[bn * 3 + 2];
    const float x = lx * 95.0f;   // scale = [W-1, H-1, D-1] = 95
    const float y = ly * 95.0f;
    const float z = lz * 95.0f;

    // phase A: tables
    if (tid < 96) {
        const float fi = (float)tid;
        const float dx = fi - x, dy = fi - y, dz = fi - z;
        ew_s[tid] = __expf(-dx * dx * 0.125f);   // 1/(2*sigma^2) = 1/8
        eh_s[tid] = __expf(-dy * dy * 0.125f);
        ed_s[tid] = __expf(-dz * dz * 0.125f);
    }
    __syncthreads();

    // phase B: sums via wave-0 shuffle reduce (96 = 64 + 32)
    if (tid < 64) {
        float a = ew_s[tid], b = eh_s[tid], c = ed_s[tid];
        if (tid < 32) { a += ew_s[tid + 64]; b += eh_s[tid + 64]; c += ed_s[tid + 64]; }
        for (int off = 32; off > 0; off >>= 1) {
            a += __shfl_down(a, off, 64);
            b += __shfl_down(b, off, 64);
            c += __shfl_down(c, off, 64);
        }
        if (tid == 0) { sums_s[0] = a; sums_s[1] = b; sums_s[2] = c; }
    }
    __syncthreads();

    const float s   = sums_s[0] * sums_s[1] * sums_s[2];
    const float inv = (s > 0.0f) ? (1.0f / s) : 1.0f;   // jnp.where(s>0, hm/s, hm)
    if (tid < 96) fh_s[tid] = eh_s[tid] * inv;
    __syncthreads();

    // per-thread static indices: h = h0 + 16k, w4 fixed
    const int h0 = tid / W4R;
    const int w4 = tid - h0 * W4R;
    const float4 e = reinterpret_cast<const float4*>(ew_s)[w4];
    float fhr[6];
    #pragma unroll
    for (int k = 0; k < 6; ++k) fhr[k] = fh_s[h0 + 16 * k];

    // phase C: stream DG slices (contiguous 72 KB, coalesced float4),
    // 12 independent loads in flight
    const float4* p0 = pred + (size_t)(bn * DD + d0) * SLICE4 + tid;
    float acc = 0.0f;
    #pragma unroll
    for (int dd = 0; dd < DG; ++dd) {
        const float edv = ed_s[d0 + dd];         // LDS broadcast, once/slice
        #pragma unroll
        for (int k = 0; k < 6; ++k) {
            const float4 p = p0[dd * SLICE4 + k * NT];
            const float  f = fhr[k] * edv;
            acc += fabsf(p.x - e.x * f) + fabsf(p.y - e.y * f)
                 + fabsf(p.z - e.z * f) + fabsf(p.w - e.w * f);
        }
    }
    acc *= (lx >= 0.0f) ? 1.0f : 0.0f;           // validity mask (block-uniform)

    // block reduce -> one partial per block
    for (int off = 32; off > 0; off >>= 1)
        acc += __shfl_down(acc, off, 64);
    const int lane = tid & 63;
    const int wid  = tid >> 6;
    if (lane == 0) wsum[wid] = acc;
    __syncthreads();
    if (tid == 0) {
        float t2 = 0.0f;
        #pragma unroll
        for (int i = 0; i < NT / 64; ++i) t2 += wsum[i];
        part[bx] = t2;
    }
}

// ---------------------------------------------------------------------------
// Kernel 2: reduce 3648 partials + validity count, write final scalar.
// ---------------------------------------------------------------------------
__global__ void __launch_bounds__(512) finalize_kernel(
        const float* __restrict__ part,
        const float* __restrict__ labels,
        float* __restrict__ out) {
    const int tid = threadIdx.x;

    float acc = 0.0f;
    #pragma unroll
    for (int i = tid; i < NBLK; i += 512) acc += part[i];
    float cnt = (tid < BN) ? ((labels[tid * 3] >= 0.0f) ? 1.0f : 0.0f) : 0.0f;

    for (int off = 32; off > 0; off >>= 1) {
        acc += __shfl_down(acc, off, 64);
        cnt += __shfl_down(cnt, off, 64);
    }
    __shared__ float wsA[8], wsC[8];
    const int lane = tid & 63;
    const int wid  = tid >> 6;
    if (lane == 0) { wsA[wid] = acc; wsC[wid] = cnt; }
    __syncthreads();
    if (tid == 0) {
        float tot = 0.0f, c = 0.0f;
        #pragma unroll
        for (int i = 0; i < 8; ++i) { tot += wsA[i]; c += wsC[i]; }
        out[0] = tot / (c + 1e-8f);
    }
}

extern "C" void kernel_launch(void* const* d_in, const int* in_sizes, int n_in,
                              void* d_out, int out_size, void* d_ws, size_t ws_size,
                              hipStream_t stream) {
    const float* pred   = (const float*)d_in[0];   // (4,19,96,96,96) f32
    const float* labels = (const float*)d_in[1];   // (4,19,3) f32
    float* out = (float*)d_out;

    float* part = (float*)d_ws;                    // 3648 floats

    loss_kernel<<<NBLK, NT, 0, stream>>>(labels, (const float4*)pred, part);
    finalize_kernel<<<1, 512, 0, stream>>>(part, labels, out);
}